// Round 4
// baseline (345.520 us; speedup 1.0000x reference)
//
#include <hip/hip_runtime.h>
#include <cstdint>

// MultiHeadAttention with LoRA on Q/V.  B=4,S=2048,D=1024,H=16,HD=64,RANK=16,scale=2.0
// R4: attention rebuilt on 32x32x16 MFMA.  P stays in registers: the S^T
// C-layout (col=lane&31=q) matches the PV A-operand lane mapping; the k-half
// exchange is done with v_permlane32_swap_b32 (4 per tile).  No P LDS buffer,
// mask folded into MFMA accumulator init, 4 blocks/CU (128 q/block, kv-tile 32,
// double-buffered K/V).  GEMMs unchanged from R3; prep fused to one launch.

#define D_DIM 1024
#define S_DIM 2048
#define B_DIM 4
#define H_DIM 16
#define HD_DIM 64
#define M_DIM 8192
#define LOG2E 1.44269504f

typedef __bf16 bf16;
typedef __bf16 bf16x4v __attribute__((ext_vector_type(4)));
typedef __bf16 bf16x8 __attribute__((ext_vector_type(8)));
typedef float f32x4 __attribute__((ext_vector_type(4)));
typedef float f32x16 __attribute__((ext_vector_type(16)));

typedef __attribute__((address_space(1))) void* as1p;
typedef __attribute__((address_space(3))) void* as3p;

__device__ __forceinline__ void gll16(const void* g, void* l) {
  __builtin_amdgcn_global_load_lds((as1p)(g), (as3p)(l), 16, 0, 0);
}

__device__ __forceinline__ unsigned pack_bf16x2(float a, float b) {
  union { __bf16 h[2]; unsigned u; } u_;
  u_.h[0] = (bf16)a; u_.h[1] = (bf16)b;
  return u_.u;
}

// v_permlane32_swap_b32: vdst[i+32] <-> src0[i]  (gfx950)
__device__ __forceinline__ void plswap32(unsigned& a, unsigned& b) {
  asm("v_permlane32_swap_b32 %0, %1" : "+v"(a), "+v"(b));
}

// ---------------------------------------------------------------- conv x -> bf16
__global__ void convert_x_kernel(const float* __restrict__ x, bf16* __restrict__ xb) {
  const int i = (blockIdx.x * 256 + threadIdx.x) * 8;
  const float4 a = *(const float4*)(x + i);
  const float4 b = *(const float4*)(x + i + 4);
  bf16x8 o;
  o[0] = (bf16)a.x; o[1] = (bf16)a.y; o[2] = (bf16)a.z; o[3] = (bf16)a.w;
  o[4] = (bf16)b.x; o[5] = (bf16)b.y; o[6] = (bf16)b.z; o[7] = (bf16)b.w;
  *(bf16x8*)(xb + i) = o;
}

// --------------------------------------- fused weight prep: W_eff = W + 2*Bm@A
__global__ void prep_w4_kernel(const float* __restrict__ Wq, const float* __restrict__ Aq,
                               const float* __restrict__ Bq, const float* __restrict__ Wk,
                               const float* __restrict__ Wv, const float* __restrict__ Av,
                               const float* __restrict__ Bv, const float* __restrict__ Wo,
                               bf16* __restrict__ wqkv, bf16* __restrict__ wo) {
  const int sel = blockIdx.y;  // 0=Q 1=K 2=V 3=O
  const float* W = (sel == 0) ? Wq : (sel == 1) ? Wk : (sel == 2) ? Wv : Wo;
  const float* A = (sel == 0) ? Aq : (sel == 2) ? Av : nullptr;
  const float* Bm = (sel == 0) ? Bq : (sel == 2) ? Bv : nullptr;
  bf16* out = (sel == 3) ? wo : wqkv + (size_t)sel * D_DIM * D_DIM;
  const int i = blockIdx.x * 256 + threadIdx.x;
  const int n = i >> 10, k = i & (D_DIM - 1);
  float w = W[i];
  if (A) {
    float acc = 0.f;
#pragma unroll
    for (int r = 0; r < 16; ++r) acc = fmaf(Bm[n * 16 + r], A[r * D_DIM + k], acc);
    w += 2.0f * acc;  // SCALING = 32/16
  }
  out[i] = (bf16)w;
}

// ----------------------------------------------- fused QKV GEMM (N=3072), dbuf
__global__ __launch_bounds__(256) void gemm_qkv_kernel(
    const bf16* __restrict__ X, const bf16* __restrict__ Wqkv,
    const float* __restrict__ bq, const float* __restrict__ bk,
    const float* __restrict__ bv, bf16* __restrict__ Qo, bf16* __restrict__ Ko,
    bf16* __restrict__ Vo) {
  __shared__ __attribute__((aligned(16))) bf16 As[2][128 * 64];
  __shared__ __attribute__((aligned(16))) bf16 Bs[2][128 * 64];
  const int tid = threadIdx.x;
  const int wave = tid >> 6, lane = tid & 63;
  const int quad = lane >> 4, l16 = lane & 15;
  const int m0 = blockIdx.x * 128, n0 = blockIdx.y * 128;
  const int wm = (wave >> 1) * 64, wn = (wave & 1) * 64;
  const int srow = lane >> 3, sblk = lane & 7;

  const f32x4 zero = {0.f, 0.f, 0.f, 0.f};
  f32x4 acc[4][4];
#pragma unroll
  for (int mi = 0; mi < 4; ++mi)
#pragma unroll
    for (int ni = 0; ni < 4; ++ni) acc[mi][ni] = zero;

  auto stage = [&](int kt) {
    const int buf = kt & 1, kb = kt * 64;
#pragma unroll
    for (int it = 0; it < 4; ++it) {
      const int c = it * 4 + wave;
      const int row = c * 8 + srow;
      const int b = sblk ^ (row & 7);
      gll16(X + (size_t)(m0 + row) * D_DIM + kb + b * 8, &As[buf][c * 512 + lane * 8]);
      gll16(Wqkv + (size_t)(n0 + row) * D_DIM + kb + b * 8, &Bs[buf][c * 512 + lane * 8]);
    }
  };
  stage(0);

  for (int kt = 0; kt < D_DIM / 64; ++kt) {
    __syncthreads();
    if (kt + 1 < D_DIM / 64) stage(kt + 1);
    const bf16* as_ = &As[kt & 1][0];
    const bf16* bs_ = &Bs[kt & 1][0];
#pragma unroll
    for (int ks = 0; ks < 2; ++ks) {
      bf16x8 af[4], bfr[4];
#pragma unroll
      for (int mi = 0; mi < 4; ++mi) {
        const int row = wm + mi * 16 + l16;
        af[mi] = *(const bf16x8*)(as_ + row * 64 + (((ks * 4 + quad) ^ (row & 7)) * 8));
      }
#pragma unroll
      for (int ni = 0; ni < 4; ++ni) {
        const int row = wn + ni * 16 + l16;
        bfr[ni] = *(const bf16x8*)(bs_ + row * 64 + (((ks * 4 + quad) ^ (row & 7)) * 8));
      }
#pragma unroll
      for (int mi = 0; mi < 4; ++mi)
#pragma unroll
        for (int ni = 0; ni < 4; ++ni)
          acc[mi][ni] =
              __builtin_amdgcn_mfma_f32_16x16x32_bf16(af[mi], bfr[ni], acc[mi][ni], 0, 0, 0);
    }
  }

  const int sel = n0 >> 10;  // 0=Q 1=K 2=V
  const float* bp = (sel == 0) ? bq : (sel == 1) ? bk : bv;
  const float qs = 0.125f * LOG2E;

  if (sel == 2) {  // V^T: [B,H,64,S], b64 packed stores
#pragma unroll
    for (int ni = 0; ni < 4; ++ni) {
      const int c = (n0 + wn + ni * 16 + l16) & 1023;
      const int h = c >> 6, hd = c & 63;
      const float bvv = bp[c];
#pragma unroll
      for (int mi = 0; mi < 4; ++mi) {
        const int row0 = m0 + wm + mi * 16 + quad * 4;
        const int b = row0 >> 11, s0 = row0 & (S_DIM - 1);
        bf16x4v pk;
#pragma unroll
        for (int r = 0; r < 4; ++r) pk[r] = (bf16)(acc[mi][ni][r] + bvv);
        *(bf16x4v*)(Vo + ((size_t)(b * H_DIM + h) * HD_DIM + hd) * S_DIM + s0) = pk;
      }
    }
  } else {
    bf16* O = (sel == 0) ? Qo : Ko;
#pragma unroll
    for (int ni = 0; ni < 4; ++ni) {
      const int c = (n0 + wn + ni * 16 + l16) & 1023;
      const int h = c >> 6, hd = c & 63;
      const float bvv = bp[c];
#pragma unroll
      for (int mi = 0; mi < 4; ++mi) {
#pragma unroll
        for (int r = 0; r < 4; ++r) {
          const int row = m0 + wm + mi * 16 + quad * 4 + r;
          const int b = row >> 11, s = row & (S_DIM - 1);
          float v = acc[mi][ni][r] + bvv;
          if (sel == 0) v *= qs;  // fold 1/sqrt(HD)*log2e into Q
          O[((size_t)(b * H_DIM + h) * S_DIM + s) * HD_DIM + hd] = (bf16)v;
        }
      }
    }
  }
}

// ------------------------------------------------ O-projection GEMM (fp32 out)
__global__ __launch_bounds__(256) void gemm_o_kernel(const bf16* __restrict__ X,
                                                     const bf16* __restrict__ W,
                                                     const float* __restrict__ bias,
                                                     float* __restrict__ out) {
  __shared__ __attribute__((aligned(16))) bf16 As[2][128 * 64];
  __shared__ __attribute__((aligned(16))) bf16 Bs[2][128 * 64];
  const int tid = threadIdx.x;
  const int wave = tid >> 6, lane = tid & 63;
  const int quad = lane >> 4, l16 = lane & 15;
  const int m0 = blockIdx.x * 128, n0 = blockIdx.y * 128;
  const int wm = (wave >> 1) * 64, wn = (wave & 1) * 64;
  const int srow = lane >> 3, sblk = lane & 7;

  const f32x4 zero = {0.f, 0.f, 0.f, 0.f};
  f32x4 acc[4][4];
#pragma unroll
  for (int mi = 0; mi < 4; ++mi)
#pragma unroll
    for (int ni = 0; ni < 4; ++ni) acc[mi][ni] = zero;

  auto stage = [&](int kt) {
    const int buf = kt & 1, kb = kt * 64;
#pragma unroll
    for (int it = 0; it < 4; ++it) {
      const int c = it * 4 + wave;
      const int row = c * 8 + srow;
      const int b = sblk ^ (row & 7);
      gll16(X + (size_t)(m0 + row) * D_DIM + kb + b * 8, &As[buf][c * 512 + lane * 8]);
      gll16(W + (size_t)(n0 + row) * D_DIM + kb + b * 8, &Bs[buf][c * 512 + lane * 8]);
    }
  };
  stage(0);

  for (int kt = 0; kt < D_DIM / 64; ++kt) {
    __syncthreads();
    if (kt + 1 < D_DIM / 64) stage(kt + 1);
    const bf16* as_ = &As[kt & 1][0];
    const bf16* bs_ = &Bs[kt & 1][0];
#pragma unroll
    for (int ks = 0; ks < 2; ++ks) {
      bf16x8 af[4], bfr[4];
#pragma unroll
      for (int mi = 0; mi < 4; ++mi) {
        const int row = wm + mi * 16 + l16;
        af[mi] = *(const bf16x8*)(as_ + row * 64 + (((ks * 4 + quad) ^ (row & 7)) * 8));
      }
#pragma unroll
      for (int ni = 0; ni < 4; ++ni) {
        const int row = wn + ni * 16 + l16;
        bfr[ni] = *(const bf16x8*)(bs_ + row * 64 + (((ks * 4 + quad) ^ (row & 7)) * 8));
      }
#pragma unroll
      for (int mi = 0; mi < 4; ++mi)
#pragma unroll
        for (int ni = 0; ni < 4; ++ni)
          acc[mi][ni] =
              __builtin_amdgcn_mfma_f32_16x16x32_bf16(af[mi], bfr[ni], acc[mi][ni], 0, 0, 0);
    }
  }
#pragma unroll
  for (int ni = 0; ni < 4; ++ni) {
    const int col = n0 + wn + ni * 16 + l16;
    const float bv = bias[col];
#pragma unroll
    for (int mi = 0; mi < 4; ++mi)
#pragma unroll
      for (int r = 0; r < 4; ++r) {
        const int row = m0 + wm + mi * 16 + quad * 4 + r;
        out[(size_t)row * D_DIM + col] = acc[mi][ni][r] + bv;
      }
  }
}

// ------------------------------------------------------------------ attention
// Q,K [B,H,S,64] (Q pre-scaled by 0.125*log2e); Vt [B,H,64,S]; mask [B,S];
// ctx [B,S,D] bf16.  128 q/block = 4 waves x 32 q, kv-tile 32, dbuf K/V.
// S^T = mfma_32x32x16(K_frag, Q_frag, cm_init): C col=lane&31=q, row=kv.
// P -> A-operand via 4 v_permlane32_swap_b32 (no LDS).  out = (P V)/(P 1).
__global__ __launch_bounds__(256, 4) void attn_kernel(const bf16* __restrict__ Q,
                                                      const bf16* __restrict__ K,
                                                      const bf16* __restrict__ Vt,
                                                      const float* __restrict__ mask,
                                                      bf16* __restrict__ ctx) {
  __shared__ __attribute__((aligned(16))) bf16 Ks[2][32 * 64];  // [kv][hd] swz
  __shared__ __attribute__((aligned(16))) bf16 Vs[2][64 * 32];  // [hd][kv] swz
  __shared__ __attribute__((aligned(16))) float cms[S_DIM];

  const int tid = threadIdx.x;
  const int wave = tid >> 6, lane = tid & 63;
  const int l32 = lane & 31, hh = lane >> 5;  // half-wave index
  const int bh = blockIdx.y, b = bh >> 4, head = bh & 15;
  const int q0 = blockIdx.x * 128 + wave * 32;

  // Q B-frags in registers: n=q=l32, k=hd (4 K-steps of 16)
  const bf16* Qg = Q + ((size_t)bh * S_DIM + q0 + l32) * HD_DIM;
  bf16x8 qf[4];
#pragma unroll
  for (int ks = 0; ks < 4; ++ks) qf[ks] = *(const bf16x8*)(Qg + ks * 16 + hh * 8);

  // stage cm = mask*log2e - 16  (once)
  {
    const float* mp = mask + b * S_DIM + tid * 8;
    const float4 a = *(const float4*)(mp);
    const float4 c = *(const float4*)(mp + 4);
    f32x4 r0 = {fmaf(a.x, LOG2E, -16.f), fmaf(a.y, LOG2E, -16.f),
                fmaf(a.z, LOG2E, -16.f), fmaf(a.w, LOG2E, -16.f)};
    f32x4 r1 = {fmaf(c.x, LOG2E, -16.f), fmaf(c.y, LOG2E, -16.f),
                fmaf(c.z, LOG2E, -16.f), fmaf(c.w, LOG2E, -16.f)};
    *(f32x4*)(cms + tid * 8) = r0;
    *(f32x4*)(cms + tid * 8 + 4) = r1;
  }

  bf16x8 onef;
#pragma unroll
  for (int j = 0; j < 8; ++j) onef[j] = (bf16)1.0f;

  f32x16 o[2], osum;
#pragma unroll
  for (int r = 0; r < 16; ++r) { o[0][r] = 0.f; o[1][r] = 0.f; osum[r] = 0.f; }

  const bf16* Kg0 = K + (size_t)bh * S_DIM * HD_DIM;
  const bf16* Vg0 = Vt + (size_t)bh * HD_DIM * S_DIM;

  auto stage = [&](int t) {
    const int buf = t & 1;
    {  // K tile [32 kv][64 hd]: row = tid>>3, blk = (tid&7) ^ (row&7)
      const int row = tid >> 3;
      const int blk = (tid & 7) ^ (row & 7);
      gll16(Kg0 + (size_t)(t * 32 + row) * HD_DIM + blk * 8, &Ks[buf][tid * 8]);
    }
    {  // V tile [64 hd][32 kv]: row = tid>>2, blk = (tid&3) ^ ((row>>1)&3)
      const int row = tid >> 2;
      const int blk = (tid & 3) ^ ((row >> 1) & 3);
      gll16(Vg0 + (size_t)row * S_DIM + t * 32 + blk * 8, &Vs[buf][tid * 8]);
    }
  };
  stage(0);

  for (int t = 0; t < S_DIM / 32; ++t) {
    __syncthreads();  // drains stage(t) vmem + (t==0) cms writes
    if (t + 1 < S_DIM / 32) stage(t + 1);
    const bf16* ks_ = &Ks[t & 1][0];
    const bf16* vs_ = &Vs[t & 1][0];

    // ---- S^T accumulator init from cm: reg r -> kv = (r&3)+8*(r>>2)+4*hh
    f32x16 sc;
    {
      const float* cmb = cms + t * 32 + 4 * hh;
      const f32x4 c0 = *(const f32x4*)(cmb);
      const f32x4 c1 = *(const f32x4*)(cmb + 8);
      const f32x4 c2 = *(const f32x4*)(cmb + 16);
      const f32x4 c3 = *(const f32x4*)(cmb + 24);
#pragma unroll
      for (int r = 0; r < 4; ++r) {
        sc[r] = c0[r]; sc[4 + r] = c1[r]; sc[8 + r] = c2[r]; sc[12 + r] = c3[r];
      }
    }

    // ---- S^T = K Q^T  (A: m=kv=l32, k=hd; B: n=q=l32, k=hd)
#pragma unroll
    for (int ks = 0; ks < 4; ++ks) {
      const int blk = ((ks * 2 + hh) ^ (l32 & 7));
      const bf16x8 kf = *(const bf16x8*)(ks_ + l32 * 64 + blk * 8);
      sc = __builtin_amdgcn_mfma_f32_32x32x16_bf16(kf, qf[ks], sc, 0, 0, 0);
    }

    // ---- p = exp2(s + cm), pack, transpose C->A via permlane32_swap
    unsigned p[8];
#pragma unroll
    for (int j = 0; j < 8; ++j)
      p[j] = pack_bf16x2(exp2f(sc[2 * j]), exp2f(sc[2 * j + 1]));
    plswap32(p[0], p[2]);
    plswap32(p[1], p[3]);
    plswap32(p[4], p[6]);
    plswap32(p[5], p[7]);
    union { unsigned u[4]; bf16x8 v; } pa0, pa1;
    pa0.u[0] = p[0]; pa0.u[1] = p[1]; pa0.u[2] = p[2]; pa0.u[3] = p[3];
    pa1.u[0] = p[4]; pa1.u[1] = p[5]; pa1.u[2] = p[6]; pa1.u[3] = p[7];

    // ---- O += P V ; osum += P 1   (B: n=hd=l32, k=kv)
#pragma unroll
    for (int ks = 0; ks < 2; ++ks) {
      const bf16x8 pa = ks ? pa1.v : pa0.v;
#pragma unroll
      for (int nh = 0; nh < 2; ++nh) {
        const int row = nh * 32 + l32;
        const int blk = ((ks * 2 + hh) ^ ((row >> 1) & 3));
        const bf16x8 vf = *(const bf16x8*)(vs_ + row * 32 + blk * 8);
        o[nh] = __builtin_amdgcn_mfma_f32_32x32x16_bf16(pa, vf, o[nh], 0, 0, 0);
      }
      osum = __builtin_amdgcn_mfma_f32_32x32x16_bf16(pa, onef, osum, 0, 0, 0);
    }
  }

  // epilogue: out = o / osum (lane-local); row q = (r&3)+8*(r>>2)+4*hh
#pragma unroll
  for (int r = 0; r < 16; ++r) {
    const float inv = 1.0f / osum[r];
    const int s = q0 + (r & 3) + 8 * (r >> 2) + 4 * hh;
    bf16* cp = ctx + ((size_t)b * S_DIM + s) * D_DIM + head * 64 + l32;
    cp[0] = (bf16)(o[0][r] * inv);
    cp[32] = (bf16)(o[1][r] * inv);
  }
}

// ------------------------------------------------------------------ launch
extern "C" void kernel_launch(void* const* d_in, const int* in_sizes, int n_in,
                              void* d_out, int out_size, void* d_ws, size_t ws_size,
                              hipStream_t stream) {
  const float* x    = (const float*)d_in[0];
  const float* mask = (const float*)d_in[1];
  const float* Wq   = (const float*)d_in[2];
  const float* bq   = (const float*)d_in[3];
  const float* Aq   = (const float*)d_in[4];
  const float* Bq   = (const float*)d_in[5];
  const float* Wk   = (const float*)d_in[6];
  const float* bk   = (const float*)d_in[7];
  const float* Wv   = (const float*)d_in[8];
  const float* bv   = (const float*)d_in[9];
  const float* Av   = (const float*)d_in[10];
  const float* Bv   = (const float*)d_in[11];
  const float* Wo   = (const float*)d_in[12];
  const float* bo   = (const float*)d_in[13];
  float* out = (float*)d_out;

  bf16* xb   = (bf16*)d_ws;                        // 16.8 MB (dead after QKV GEMM)
  bf16* wqkv = xb + (size_t)M_DIM * D_DIM;         // 6.3 MB  [wq;wk;wv]
  bf16* wo   = wqkv + (size_t)3 * D_DIM * D_DIM;   // 2.1 MB
  bf16* Qw   = wo + (size_t)D_DIM * D_DIM;         // 16.8 MB each
  bf16* Kw   = Qw + (size_t)M_DIM * D_DIM;
  bf16* Vw   = Kw + (size_t)M_DIM * D_DIM;
  bf16* Cw   = xb;                                 // alias: ctx reuses xb

  convert_x_kernel<<<M_DIM * D_DIM / (256 * 8), 256, 0, stream>>>(x, xb);
  prep_w4_kernel<<<dim3(D_DIM * D_DIM / 256, 4), 256, 0, stream>>>(
      Wq, Aq, Bq, Wk, Wv, Av, Bv, Wo, wqkv, wo);

  gemm_qkv_kernel<<<dim3(M_DIM / 128, 3 * D_DIM / 128), 256, 0, stream>>>(
      xb, wqkv, bq, bk, bv, Qw, Kw, Vw);

  attn_kernel<<<dim3(S_DIM / 128, B_DIM * H_DIM), 256, 0, stream>>>(Qw, Kw, Vw, mask, Cw);

  gemm_o_kernel<<<dim3(M_DIM / 128, D_DIM / 128), 256, 0, stream>>>(Cw, wo, bo, out);
}

// Round 7
// 337.652 us; speedup vs baseline: 1.0233x; 1.0233x over previous
//
#include <hip/hip_runtime.h>
#include <cstdint>

// MultiHeadAttention with LoRA on Q/V.  B=4,S=2048,D=1024,H=16,HD=64,RANK=16,scale=2.0
// R7 = R4 (last fully-passing kernel) + ONE delta in attention: a second q-sub
// per wave (64 q/wave, 256 q/block) sharing the K/V/cm fragments.  All staging,
// swizzles, mask handling, and numerics are byte-identical to R4.  vscale
// machinery from R5/R6 reverted (contains an unidentified defect).

#define D_DIM 1024
#define S_DIM 2048
#define B_DIM 4
#define H_DIM 16
#define HD_DIM 64
#define M_DIM 8192
#define LOG2E 1.44269504f

typedef __bf16 bf16;
typedef __bf16 bf16x4v __attribute__((ext_vector_type(4)));
typedef __bf16 bf16x8 __attribute__((ext_vector_type(8)));
typedef float f32x4 __attribute__((ext_vector_type(4)));
typedef float f32x16 __attribute__((ext_vector_type(16)));

typedef __attribute__((address_space(1))) void* as1p;
typedef __attribute__((address_space(3))) void* as3p;

__device__ __forceinline__ void gll16(const void* g, void* l) {
  __builtin_amdgcn_global_load_lds((as1p)(g), (as3p)(l), 16, 0, 0);
}

__device__ __forceinline__ unsigned pack_bf16x2(float a, float b) {
  union { __bf16 h[2]; unsigned u; } u_;
  u_.h[0] = (bf16)a; u_.h[1] = (bf16)b;
  return u_.u;
}

// v_permlane32_swap_b32: vdst[i+32] <-> src0[i]  (gfx950)
__device__ __forceinline__ void plswap32(unsigned& a, unsigned& b) {
  asm("v_permlane32_swap_b32 %0, %1" : "+v"(a), "+v"(b));
}

// ---------------------------------------------------------------- conv x -> bf16
__global__ void convert_x_kernel(const float* __restrict__ x, bf16* __restrict__ xb) {
  const int i = (blockIdx.x * 256 + threadIdx.x) * 8;
  const float4 a = *(const float4*)(x + i);
  const float4 b = *(const float4*)(x + i + 4);
  bf16x8 o;
  o[0] = (bf16)a.x; o[1] = (bf16)a.y; o[2] = (bf16)a.z; o[3] = (bf16)a.w;
  o[4] = (bf16)b.x; o[5] = (bf16)b.y; o[6] = (bf16)b.z; o[7] = (bf16)b.w;
  *(bf16x8*)(xb + i) = o;
}

// --------------------------------------- fused weight prep: W_eff = W + 2*Bm@A
__global__ void prep_w4_kernel(const float* __restrict__ Wq, const float* __restrict__ Aq,
                               const float* __restrict__ Bq, const float* __restrict__ Wk,
                               const float* __restrict__ Wv, const float* __restrict__ Av,
                               const float* __restrict__ Bv, const float* __restrict__ Wo,
                               bf16* __restrict__ wqkv, bf16* __restrict__ wo) {
  const int sel = blockIdx.y;  // 0=Q 1=K 2=V 3=O
  const float* W = (sel == 0) ? Wq : (sel == 1) ? Wk : (sel == 2) ? Wv : Wo;
  const float* A = (sel == 0) ? Aq : (sel == 2) ? Av : nullptr;
  const float* Bm = (sel == 0) ? Bq : (sel == 2) ? Bv : nullptr;
  bf16* out = (sel == 3) ? wo : wqkv + (size_t)sel * D_DIM * D_DIM;
  const int i = blockIdx.x * 256 + threadIdx.x;
  const int n = i >> 10, k = i & (D_DIM - 1);
  float w = W[i];
  if (A) {
    float acc = 0.f;
#pragma unroll
    for (int r = 0; r < 16; ++r) acc = fmaf(Bm[n * 16 + r], A[r * D_DIM + k], acc);
    w += 2.0f * acc;  // SCALING = 32/16
  }
  out[i] = (bf16)w;
}

// ----------------------------------------------- fused QKV GEMM (N=3072), dbuf
__global__ __launch_bounds__(256) void gemm_qkv_kernel(
    const bf16* __restrict__ X, const bf16* __restrict__ Wqkv,
    const float* __restrict__ bq, const float* __restrict__ bk,
    const float* __restrict__ bv, bf16* __restrict__ Qo, bf16* __restrict__ Ko,
    bf16* __restrict__ Vo) {
  __shared__ __attribute__((aligned(16))) bf16 As[2][128 * 64];
  __shared__ __attribute__((aligned(16))) bf16 Bs[2][128 * 64];
  const int tid = threadIdx.x;
  const int wave = tid >> 6, lane = tid & 63;
  const int quad = lane >> 4, l16 = lane & 15;
  const int m0 = blockIdx.x * 128, n0 = blockIdx.y * 128;
  const int wm = (wave >> 1) * 64, wn = (wave & 1) * 64;
  const int srow = lane >> 3, sblk = lane & 7;

  const f32x4 zero = {0.f, 0.f, 0.f, 0.f};
  f32x4 acc[4][4];
#pragma unroll
  for (int mi = 0; mi < 4; ++mi)
#pragma unroll
    for (int ni = 0; ni < 4; ++ni) acc[mi][ni] = zero;

  auto stage = [&](int kt) {
    const int buf = kt & 1, kb = kt * 64;
#pragma unroll
    for (int it = 0; it < 4; ++it) {
      const int c = it * 4 + wave;
      const int row = c * 8 + srow;
      const int b = sblk ^ (row & 7);
      gll16(X + (size_t)(m0 + row) * D_DIM + kb + b * 8, &As[buf][c * 512 + lane * 8]);
      gll16(Wqkv + (size_t)(n0 + row) * D_DIM + kb + b * 8, &Bs[buf][c * 512 + lane * 8]);
    }
  };
  stage(0);

  for (int kt = 0; kt < D_DIM / 64; ++kt) {
    __syncthreads();
    if (kt + 1 < D_DIM / 64) stage(kt + 1);
    const bf16* as_ = &As[kt & 1][0];
    const bf16* bs_ = &Bs[kt & 1][0];
#pragma unroll
    for (int ks = 0; ks < 2; ++ks) {
      bf16x8 af[4], bfr[4];
#pragma unroll
      for (int mi = 0; mi < 4; ++mi) {
        const int row = wm + mi * 16 + l16;
        af[mi] = *(const bf16x8*)(as_ + row * 64 + (((ks * 4 + quad) ^ (row & 7)) * 8));
      }
#pragma unroll
      for (int ni = 0; ni < 4; ++ni) {
        const int row = wn + ni * 16 + l16;
        bfr[ni] = *(const bf16x8*)(bs_ + row * 64 + (((ks * 4 + quad) ^ (row & 7)) * 8));
      }
#pragma unroll
      for (int mi = 0; mi < 4; ++mi)
#pragma unroll
        for (int ni = 0; ni < 4; ++ni)
          acc[mi][ni] =
              __builtin_amdgcn_mfma_f32_16x16x32_bf16(af[mi], bfr[ni], acc[mi][ni], 0, 0, 0);
    }
  }

  const int sel = n0 >> 10;  // 0=Q 1=K 2=V
  const float* bp = (sel == 0) ? bq : (sel == 1) ? bk : bv;
  const float qs = 0.125f * LOG2E;

  if (sel == 2) {  // V^T: [B,H,64,S], b64 packed stores
#pragma unroll
    for (int ni = 0; ni < 4; ++ni) {
      const int c = (n0 + wn + ni * 16 + l16) & 1023;
      const int h = c >> 6, hd = c & 63;
      const float bvv = bp[c];
#pragma unroll
      for (int mi = 0; mi < 4; ++mi) {
        const int row0 = m0 + wm + mi * 16 + quad * 4;
        const int b = row0 >> 11, s0 = row0 & (S_DIM - 1);
        bf16x4v pk;
#pragma unroll
        for (int r = 0; r < 4; ++r) pk[r] = (bf16)(acc[mi][ni][r] + bvv);
        *(bf16x4v*)(Vo + ((size_t)(b * H_DIM + h) * HD_DIM + hd) * S_DIM + s0) = pk;
      }
    }
  } else {
    bf16* O = (sel == 0) ? Qo : Ko;
#pragma unroll
    for (int ni = 0; ni < 4; ++ni) {
      const int c = (n0 + wn + ni * 16 + l16) & 1023;
      const int h = c >> 6, hd = c & 63;
      const float bvv = bp[c];
#pragma unroll
      for (int mi = 0; mi < 4; ++mi) {
#pragma unroll
        for (int r = 0; r < 4; ++r) {
          const int row = m0 + wm + mi * 16 + quad * 4 + r;
          const int b = row >> 11, s = row & (S_DIM - 1);
          float v = acc[mi][ni][r] + bvv;
          if (sel == 0) v *= qs;  // fold 1/sqrt(HD)*log2e into Q
          O[((size_t)(b * H_DIM + h) * S_DIM + s) * HD_DIM + hd] = (bf16)v;
        }
      }
    }
  }
}

// ------------------------------------------------ O-projection GEMM (fp32 out)
__global__ __launch_bounds__(256) void gemm_o_kernel(const bf16* __restrict__ X,
                                                     const bf16* __restrict__ W,
                                                     const float* __restrict__ bias,
                                                     float* __restrict__ out) {
  __shared__ __attribute__((aligned(16))) bf16 As[2][128 * 64];
  __shared__ __attribute__((aligned(16))) bf16 Bs[2][128 * 64];
  const int tid = threadIdx.x;
  const int wave = tid >> 6, lane = tid & 63;
  const int quad = lane >> 4, l16 = lane & 15;
  const int m0 = blockIdx.x * 128, n0 = blockIdx.y * 128;
  const int wm = (wave >> 1) * 64, wn = (wave & 1) * 64;
  const int srow = lane >> 3, sblk = lane & 7;

  const f32x4 zero = {0.f, 0.f, 0.f, 0.f};
  f32x4 acc[4][4];
#pragma unroll
  for (int mi = 0; mi < 4; ++mi)
#pragma unroll
    for (int ni = 0; ni < 4; ++ni) acc[mi][ni] = zero;

  auto stage = [&](int kt) {
    const int buf = kt & 1, kb = kt * 64;
#pragma unroll
    for (int it = 0; it < 4; ++it) {
      const int c = it * 4 + wave;
      const int row = c * 8 + srow;
      const int b = sblk ^ (row & 7);
      gll16(X + (size_t)(m0 + row) * D_DIM + kb + b * 8, &As[buf][c * 512 + lane * 8]);
      gll16(W + (size_t)(n0 + row) * D_DIM + kb + b * 8, &Bs[buf][c * 512 + lane * 8]);
    }
  };
  stage(0);

  for (int kt = 0; kt < D_DIM / 64; ++kt) {
    __syncthreads();
    if (kt + 1 < D_DIM / 64) stage(kt + 1);
    const bf16* as_ = &As[kt & 1][0];
    const bf16* bs_ = &Bs[kt & 1][0];
#pragma unroll
    for (int ks = 0; ks < 2; ++ks) {
      bf16x8 af[4], bfr[4];
#pragma unroll
      for (int mi = 0; mi < 4; ++mi) {
        const int row = wm + mi * 16 + l16;
        af[mi] = *(const bf16x8*)(as_ + row * 64 + (((ks * 4 + quad) ^ (row & 7)) * 8));
      }
#pragma unroll
      for (int ni = 0; ni < 4; ++ni) {
        const int row = wn + ni * 16 + l16;
        bfr[ni] = *(const bf16x8*)(bs_ + row * 64 + (((ks * 4 + quad) ^ (row & 7)) * 8));
      }
#pragma unroll
      for (int mi = 0; mi < 4; ++mi)
#pragma unroll
        for (int ni = 0; ni < 4; ++ni)
          acc[mi][ni] =
              __builtin_amdgcn_mfma_f32_16x16x32_bf16(af[mi], bfr[ni], acc[mi][ni], 0, 0, 0);
    }
  }
#pragma unroll
  for (int ni = 0; ni < 4; ++ni) {
    const int col = n0 + wn + ni * 16 + l16;
    const float bv = bias[col];
#pragma unroll
    for (int mi = 0; mi < 4; ++mi)
#pragma unroll
      for (int r = 0; r < 4; ++r) {
        const int row = m0 + wm + mi * 16 + quad * 4 + r;
        out[(size_t)row * D_DIM + col] = acc[mi][ni][r] + bv;
      }
  }
}

// ------------------------------------------------------------------ attention
// Q,K [B,H,S,64] (Q pre-scaled by 0.125*log2e); Vt [B,H,64,S]; mask [B,S];
// ctx [B,S,D] bf16.  256 q/block = 4 waves x 64 q (2 q-subs of 32 sharing the
// K/V/cm fragments), kv-tile 32, dbuf.  S^T = mfma_32x32x16(K, Q, cm_init):
// C col=lane&31=q, row=kv.  P -> A-operand via 4 v_permlane32_swap_b32.
// p = exp2(s + mask*log2e - 16); out = (P V)/(P 1) — shift cancels.
__global__ __launch_bounds__(256, 2) void attn_kernel(const bf16* __restrict__ Q,
                                                      const bf16* __restrict__ K,
                                                      const bf16* __restrict__ Vt,
                                                      const float* __restrict__ mask,
                                                      bf16* __restrict__ ctx) {
  __shared__ __attribute__((aligned(16))) bf16 Ks[2][32 * 64];  // [kv][hd] swz
  __shared__ __attribute__((aligned(16))) bf16 Vs[2][64 * 32];  // [hd][kv] swz
  __shared__ __attribute__((aligned(16))) float cms[S_DIM];

  const int tid = threadIdx.x;
  const int wave = tid >> 6, lane = tid & 63;
  const int l32 = lane & 31, hh = lane >> 5;  // half-wave index
  const int bh = blockIdx.y, b = bh >> 4, head = bh & 15;
  const int q0 = blockIdx.x * 256 + wave * 64;  // 2 q-subs of 32 per wave

  // Q B-frags in registers: n=q=l32, k=hd (4 K-steps of 16), per q-sub
  const bf16* Qg = Q + ((size_t)bh * S_DIM + q0) * HD_DIM;
  bf16x8 qf[2][4];
#pragma unroll
  for (int qs = 0; qs < 2; ++qs)
#pragma unroll
    for (int ks = 0; ks < 4; ++ks)
      qf[qs][ks] = *(const bf16x8*)(Qg + (qs * 32 + l32) * HD_DIM + ks * 16 + hh * 8);

  // stage cm = mask*log2e - 16  (once)
  {
    const float* mp = mask + b * S_DIM + tid * 8;
    const float4 a = *(const float4*)(mp);
    const float4 c = *(const float4*)(mp + 4);
    f32x4 r0 = {fmaf(a.x, LOG2E, -16.f), fmaf(a.y, LOG2E, -16.f),
                fmaf(a.z, LOG2E, -16.f), fmaf(a.w, LOG2E, -16.f)};
    f32x4 r1 = {fmaf(c.x, LOG2E, -16.f), fmaf(c.y, LOG2E, -16.f),
                fmaf(c.z, LOG2E, -16.f), fmaf(c.w, LOG2E, -16.f)};
    *(f32x4*)(cms + tid * 8) = r0;
    *(f32x4*)(cms + tid * 8 + 4) = r1;
  }

  bf16x8 onef;
#pragma unroll
  for (int j = 0; j < 8; ++j) onef[j] = (bf16)1.0f;

  f32x16 o[2][2], osum[2];
#pragma unroll
  for (int qs = 0; qs < 2; ++qs)
#pragma unroll
    for (int r = 0; r < 16; ++r) { o[qs][0][r] = 0.f; o[qs][1][r] = 0.f; osum[qs][r] = 0.f; }

  const bf16* Kg0 = K + (size_t)bh * S_DIM * HD_DIM;
  const bf16* Vg0 = Vt + (size_t)bh * HD_DIM * S_DIM;

  auto stage = [&](int t) {
    const int buf = t & 1;
    {  // K tile [32 kv][64 hd]: row = tid>>3, blk = (tid&7) ^ (row&7)
      const int row = tid >> 3;
      const int blk = (tid & 7) ^ (row & 7);
      gll16(Kg0 + (size_t)(t * 32 + row) * HD_DIM + blk * 8, &Ks[buf][tid * 8]);
    }
    {  // V tile [64 hd][32 kv]: row = tid>>2, blk = (tid&3) ^ ((row>>1)&3)
      const int row = tid >> 2;
      const int blk = (tid & 3) ^ ((row >> 1) & 3);
      gll16(Vg0 + (size_t)row * S_DIM + t * 32 + blk * 8, &Vs[buf][tid * 8]);
    }
  };
  stage(0);

  for (int t = 0; t < S_DIM / 32; ++t) {
    __syncthreads();  // drains stage(t) vmem + (t==0) cms writes
    if (t + 1 < S_DIM / 32) stage(t + 1);
    const bf16* ks_ = &Ks[t & 1][0];
    const bf16* vs_ = &Vs[t & 1][0];

    // ---- S^T accumulator init from cm: reg r -> kv = (r&3)+8*(r>>2)+4*hh
    f32x16 sc0, sc1;
    {
      const float* cmb = cms + t * 32 + 4 * hh;
      const f32x4 c0 = *(const f32x4*)(cmb);
      const f32x4 c1 = *(const f32x4*)(cmb + 8);
      const f32x4 c2 = *(const f32x4*)(cmb + 16);
      const f32x4 c3 = *(const f32x4*)(cmb + 24);
#pragma unroll
      for (int r = 0; r < 4; ++r) {
        sc0[r] = c0[r]; sc0[4 + r] = c1[r]; sc0[8 + r] = c2[r]; sc0[12 + r] = c3[r];
        sc1[r] = c0[r]; sc1[4 + r] = c1[r]; sc1[8 + r] = c2[r]; sc1[12 + r] = c3[r];
      }
    }

    // ---- S^T = K Q^T for both q-subs (K A-frags shared)
#pragma unroll
    for (int ks = 0; ks < 4; ++ks) {
      const int blk = ((ks * 2 + hh) ^ (l32 & 7));
      const bf16x8 kf = *(const bf16x8*)(ks_ + l32 * 64 + blk * 8);
      sc0 = __builtin_amdgcn_mfma_f32_32x32x16_bf16(kf, qf[0][ks], sc0, 0, 0, 0);
      sc1 = __builtin_amdgcn_mfma_f32_32x32x16_bf16(kf, qf[1][ks], sc1, 0, 0, 0);
    }

    // ---- V B-frags (shared by both q-subs)
    bf16x8 vf[2][2];
#pragma unroll
    for (int ks = 0; ks < 2; ++ks)
#pragma unroll
      for (int nh = 0; nh < 2; ++nh) {
        const int row = nh * 32 + l32;
        const int blk = ((ks * 2 + hh) ^ ((row >> 1) & 3));
        vf[nh][ks] = *(const bf16x8*)(vs_ + row * 32 + blk * 8);
      }

    // ---- per q-sub: exp2, pack, permlane transpose, PV + osum
#pragma unroll
    for (int qs = 0; qs < 2; ++qs) {
      const f32x16 sc = qs ? sc1 : sc0;
      unsigned p[8];
#pragma unroll
      for (int j = 0; j < 8; ++j)
        p[j] = pack_bf16x2(exp2f(sc[2 * j]), exp2f(sc[2 * j + 1]));
      plswap32(p[0], p[2]);
      plswap32(p[1], p[3]);
      plswap32(p[4], p[6]);
      plswap32(p[5], p[7]);
      union { unsigned u[4]; bf16x8 v; } pa0, pa1;
      pa0.u[0] = p[0]; pa0.u[1] = p[1]; pa0.u[2] = p[2]; pa0.u[3] = p[3];
      pa1.u[0] = p[4]; pa1.u[1] = p[5]; pa1.u[2] = p[6]; pa1.u[3] = p[7];
#pragma unroll
      for (int ks = 0; ks < 2; ++ks) {
        const bf16x8 pa = ks ? pa1.v : pa0.v;
        o[qs][0] = __builtin_amdgcn_mfma_f32_32x32x16_bf16(pa, vf[0][ks], o[qs][0], 0, 0, 0);
        o[qs][1] = __builtin_amdgcn_mfma_f32_32x32x16_bf16(pa, vf[1][ks], o[qs][1], 0, 0, 0);
        osum[qs] = __builtin_amdgcn_mfma_f32_32x32x16_bf16(pa, onef, osum[qs], 0, 0, 0);
      }
    }
  }

  // epilogue: out = o / osum (lane-local); q = (r&3)+8*(r>>2)+4*hh
#pragma unroll
  for (int qs = 0; qs < 2; ++qs)
#pragma unroll
    for (int r = 0; r < 16; ++r) {
      const float inv = 1.0f / osum[qs][r];
      const int s = q0 + qs * 32 + (r & 3) + 8 * (r >> 2) + 4 * hh;
      bf16* cp = ctx + ((size_t)b * S_DIM + s) * D_DIM + head * 64 + l32;
      cp[0] = (bf16)(o[qs][0][r] * inv);
      cp[32] = (bf16)(o[qs][1][r] * inv);
    }
}

// ------------------------------------------------------------------ launch
extern "C" void kernel_launch(void* const* d_in, const int* in_sizes, int n_in,
                              void* d_out, int out_size, void* d_ws, size_t ws_size,
                              hipStream_t stream) {
  const float* x    = (const float*)d_in[0];
  const float* mask = (const float*)d_in[1];
  const float* Wq   = (const float*)d_in[2];
  const float* bq   = (const float*)d_in[3];
  const float* Aq   = (const float*)d_in[4];
  const float* Bq   = (const float*)d_in[5];
  const float* Wk   = (const float*)d_in[6];
  const float* bk   = (const float*)d_in[7];
  const float* Wv   = (const float*)d_in[8];
  const float* bv   = (const float*)d_in[9];
  const float* Av   = (const float*)d_in[10];
  const float* Bv   = (const float*)d_in[11];
  const float* Wo   = (const float*)d_in[12];
  const float* bo   = (const float*)d_in[13];
  float* out = (float*)d_out;

  bf16* xb   = (bf16*)d_ws;                        // 16.8 MB (dead after QKV GEMM)
  bf16* wqkv = xb + (size_t)M_DIM * D_DIM;         // 6.3 MB  [wq;wk;wv]
  bf16* wo   = wqkv + (size_t)3 * D_DIM * D_DIM;   // 2.1 MB
  bf16* Qw   = wo + (size_t)D_DIM * D_DIM;         // 16.8 MB each
  bf16* Kw   = Qw + (size_t)M_DIM * D_DIM;
  bf16* Vw   = Kw + (size_t)M_DIM * D_DIM;
  bf16* Cw   = xb;                                 // alias: ctx reuses xb

  convert_x_kernel<<<M_DIM * D_DIM / (256 * 8), 256, 0, stream>>>(x, xb);
  prep_w4_kernel<<<dim3(D_DIM * D_DIM / 256, 4), 256, 0, stream>>>(
      Wq, Aq, Bq, Wk, Wv, Av, Bv, Wo, wqkv, wo);

  gemm_qkv_kernel<<<dim3(M_DIM / 128, 3 * D_DIM / 128), 256, 0, stream>>>(
      xb, wqkv, bq, bk, bv, Qw, Kw, Vw);

  attn_kernel<<<dim3(S_DIM / 256, B_DIM * H_DIM), 256, 0, stream>>>(Qw, Kw, Vw, mask, Cw);

  gemm_o_kernel<<<dim3(M_DIM / 128, D_DIM / 128), 256, 0, stream>>>(Cw, wo, bo, out);
}